// Round 1
// baseline (320.801 us; speedup 1.0000x reference)
//
#include <hip/hip_runtime.h>
#include <hip/hip_bf16.h>

#define NROWS 2048
#define C0 2000
#define C1 10000
#define OSZ0 8000
#define OSZ1 40257
#define HEADSZ 2002

typedef float f32x4 __attribute__((ext_vector_type(4)));
typedef __bf16 bf16x8 __attribute__((ext_vector_type(8)));
typedef short s16x8 __attribute__((ext_vector_type(8)));

__device__ __forceinline__ unsigned short f2bf(float f) {
    unsigned int u = __float_as_uint(f);
    unsigned int r = (u + 0x7FFFu + ((u >> 16) & 1u)) >> 16;
    return (unsigned short)r;
}

__device__ __forceinline__ f32x4 mfma16(s16x8 a, s16x8 b, f32x4 c) {
    return __builtin_amdgcn_mfma_f32_16x16x32_bf16(
        __builtin_bit_cast(bf16x8, a), __builtin_bit_cast(bf16x8, b), c, 0, 0, 0);
}

// Gather x[n] = lhs[b, idx[b,k], :] converted to bf16. 2048 rows x 1024 cols.
__global__ void k_gather_x(const float* __restrict__ lhs, const int* __restrict__ idx,
                           unsigned short* __restrict__ xb) {
    int tid = blockIdx.x * 256 + threadIdx.x;      // 524288 threads
    int n = tid >> 8;
    int c = (tid & 255) << 2;
    int b = n >> 8, k = n & 255;
    int srow = idx[(b << 8) + k];
    const float4 v = *reinterpret_cast<const float4*>(
        lhs + (((size_t)b << 9) + srow) * 1024 + c);
    ushort4 o = make_ushort4(f2bf(v.x), f2bf(v.y), f2bf(v.z), f2bf(v.w));
    *reinterpret_cast<ushort4*>(xb + (size_t)n * 1024 + c) = o;
}

// fp32 [rows][cols] -> bf16 [rows_pad][cols], pad rows zeroed. cols = 1<<colshift.
__global__ void k_convert_pad(const float* __restrict__ src, unsigned short* __restrict__ dst,
                              int rows, int colshift, int rows_pad) {
    int tid = blockIdx.x * 256 + threadIdx.x;
    int e = tid << 2;
    int total = rows_pad << colshift;
    if (e >= total) return;
    int row = e >> colshift;
    ushort4 o;
    if (row < rows) {
        float4 v = *reinterpret_cast<const float4*>(src + e);
        o = make_ushort4(f2bf(v.x), f2bf(v.y), f2bf(v.z), f2bf(v.w));
    } else {
        o = make_ushort4(0, 0, 0, 0);
    }
    *reinterpret_cast<ushort4*>(dst + e) = o;
}

// Per-row clipped target columns for the three GEMMs.
__global__ void k_tcols(const int* __restrict__ tgt, int* __restrict__ tc) {
    int n = blockIdx.x * 256 + threadIdx.x;
    if (n >= NROWS) return;
    int t = tgt[n];
    tc[n] = min(t, C0 - 1);
    tc[NROWS + n] = min(max(t - C0, 0), OSZ0 - 1);
    tc[2 * NROWS + n] = min(max(t - C1, 0), OSZ1 - 1);
}

// C = A[2048][K] * B[npad][K]^T. Block = 128x128 tile, 4 waves of 64x64.
// FUSED: emit per-64-col-strip exp-sums (partial[strip][row]) + target/fixed-col logits.
// else: write bf16 activations Hout[row][col] (col < nvalid).
template <int K, bool FUSED>
__global__ __launch_bounds__(256)
void k_gemm(const unsigned short* __restrict__ A, const unsigned short* __restrict__ B,
            const float* __restrict__ bias, int nvalid,
            float* __restrict__ partial, const int* __restrict__ tcol,
            float* __restrict__ tgtv,
            int fc0, float* __restrict__ f0, int fc1, float* __restrict__ f1,
            unsigned short* __restrict__ Hout, int hstride) {
    const int lane = threadIdx.x & 63;
    const int wid = threadIdx.x >> 6;
    const int wr = wid >> 1, wc = wid & 1;
    const int g = lane >> 4, cl = lane & 15;
    const int row0 = blockIdx.x * 128 + wr * 64;
    const int col0 = blockIdx.y * 128 + wc * 64;

    f32x4 acc[4][4] = {};
    const unsigned short* Ap[4];
    const unsigned short* Bp[4];
#pragma unroll
    for (int i = 0; i < 4; ++i) {
        Ap[i] = A + (size_t)(row0 + i * 16 + cl) * K + g * 8;
        Bp[i] = B + (size_t)(col0 + i * 16 + cl) * K + g * 8;
    }

    for (int k = 0; k < K; k += 32) {
        s16x8 a[4], b[4];
#pragma unroll
        for (int i = 0; i < 4; ++i) a[i] = *reinterpret_cast<const s16x8*>(Ap[i] + k);
#pragma unroll
        for (int i = 0; i < 4; ++i) b[i] = *reinterpret_cast<const s16x8*>(Bp[i] + k);
#pragma unroll
        for (int mi = 0; mi < 4; ++mi)
#pragma unroll
            for (int ni = 0; ni < 4; ++ni)
                acc[mi][ni] = mfma16(a[mi], b[ni], acc[mi][ni]);
    }

    if (FUSED) {
        float bv[4];
        int colv[4];
#pragma unroll
        for (int ni = 0; ni < 4; ++ni) {
            int col = col0 + ni * 16 + cl;
            colv[ni] = col;
            bv[ni] = (bias != nullptr && col < nvalid) ? bias[col] : 0.f;
        }
#pragma unroll
        for (int mi = 0; mi < 4; ++mi) {
#pragma unroll
            for (int r = 0; r < 4; ++r) {
                int row = row0 + mi * 16 + g * 4 + r;
                int tc = tcol[row];
                float s = 0.f;
#pragma unroll
                for (int ni = 0; ni < 4; ++ni) {
                    int col = colv[ni];
                    if (col < nvalid) {
                        float logit = acc[mi][ni][r] + bv[ni];
                        s += __expf(logit);
                        if (col == tc) tgtv[row] = logit;
                        if (fc0 >= 0 && col == fc0) f0[row] = logit;
                        if (fc1 >= 0 && col == fc1) f1[row] = logit;
                    }
                }
#pragma unroll
                for (int off = 1; off < 16; off <<= 1) s += __shfl_xor(s, off, 64);
                if (cl == 0) partial[(size_t)(col0 >> 6) * NROWS + row] = s;
            }
        }
    } else {
#pragma unroll
        for (int mi = 0; mi < 4; ++mi) {
#pragma unroll
            for (int ni = 0; ni < 4; ++ni) {
                int col = col0 + ni * 16 + cl;
                if (col < nvalid) {
#pragma unroll
                    for (int r = 0; r < 4; ++r) {
                        int row = row0 + mi * 16 + g * 4 + r;
                        Hout[(size_t)row * hstride + col] = f2bf(acc[mi][ni][r]);
                    }
                }
            }
        }
    }
}

// Per-row: reduce partials -> lse, combine with target logits, emit out + block sums.
__global__ void k_finalize(const float* __restrict__ ph, const float* __restrict__ p0,
                           const float* __restrict__ p1, const float* __restrict__ tgh,
                           const float* __restrict__ r0, const float* __restrict__ r1,
                           const float* __restrict__ tg0, const float* __restrict__ tg1,
                           const int* __restrict__ tgt, float* __restrict__ outv,
                           float* __restrict__ bsum) {
    int n = blockIdx.x * 256 + threadIdx.x;   // 8 blocks x 256
    float sh = 0.f, s0 = 0.f, s1 = 0.f;
    for (int ct = 0; ct < 32; ++ct) sh += ph[ct * NROWS + n];
    for (int ct = 0; ct < 126; ++ct) s0 += p0[ct * NROWS + n];
    for (int ct = 0; ct < 630; ++ct) s1 += p1[ct * NROWS + n];
    float lh = __logf(sh), l0 = __logf(s0), l1 = __logf(s1);
    int t = tgt[n];
    float o;
    if (t < C0) o = tgh[n] - lh;
    else if (t < C1) o = (r0[n] - lh) + (tg0[n] - l0);
    else o = (r1[n] - lh) + (tg1[n] - l1);
    outv[n] = o;

    __shared__ float red[256];
    red[threadIdx.x] = o;
    __syncthreads();
    for (int s = 128; s > 0; s >>= 1) {
        if (threadIdx.x < s) red[threadIdx.x] += red[threadIdx.x + s];
        __syncthreads();
    }
    if (threadIdx.x == 0) bsum[blockIdx.x] = red[0];
}

__global__ void k_loss(const float* __restrict__ bsum, float* __restrict__ loss) {
    float s = 0.f;
    for (int i = 0; i < 8; ++i) s += bsum[i];
    *loss = -s / (float)NROWS;
}

extern "C" void kernel_launch(void* const* d_in, const int* in_sizes, int n_in,
                              void* d_out, int out_size, void* d_ws, size_t ws_size,
                              hipStream_t stream) {
    const int* targets   = (const int*)d_in[0];
    const float* lhs     = (const float*)d_in[1];
    // d_in[2] cls_tokens_batch: unused by reference
    const int* idx       = (const int*)d_in[3];
    const float* head_W  = (const float*)d_in[4];
    const float* head_b  = (const float*)d_in[5];
    const float* proj0_W = (const float*)d_in[6];
    const float* out0_W  = (const float*)d_in[7];
    const float* proj1_W = (const float*)d_in[8];
    const float* out1_W  = (const float*)d_in[9];

    char* ws = (char*)d_ws;
    size_t off = 0;
    auto alloc = [&](size_t bytes) -> void* {
        void* p = ws + off;
        off += (bytes + 255) & ~(size_t)255;
        return p;
    };

    unsigned short* xb   = (unsigned short*)alloc((size_t)2048 * 1024 * 2);
    unsigned short* hWb  = (unsigned short*)alloc((size_t)2048 * 1024 * 2);   // pad 2002->2048
    unsigned short* p0Wb = (unsigned short*)alloc((size_t)256 * 1024 * 2);
    unsigned short* o0Wb = (unsigned short*)alloc((size_t)8064 * 256 * 2);    // pad 8000->8064
    unsigned short* p1Wb = (unsigned short*)alloc((size_t)128 * 1024 * 2);    // pad 64->128
    unsigned short* o1Wb = (unsigned short*)alloc((size_t)40320 * 64 * 2);    // pad 40257->40320
    unsigned short* h0b  = (unsigned short*)alloc((size_t)2048 * 256 * 2);
    unsigned short* h1b  = (unsigned short*)alloc((size_t)2048 * 64 * 2);
    float* ph  = (float*)alloc((size_t)32 * 2048 * 4);
    float* p0  = (float*)alloc((size_t)126 * 2048 * 4);
    float* p1  = (float*)alloc((size_t)630 * 2048 * 4);
    float* tgh = (float*)alloc(2048 * 4);
    float* r0  = (float*)alloc(2048 * 4);
    float* r1  = (float*)alloc(2048 * 4);
    float* tg0 = (float*)alloc(2048 * 4);
    float* tg1 = (float*)alloc(2048 * 4);
    int*   tc  = (int*)alloc(3 * 2048 * 4);
    float* bsum = (float*)alloc(8 * 4);

    // --- conversions / gathers ---
    k_gather_x<<<2048, 256, 0, stream>>>(lhs, idx, xb);
    k_convert_pad<<<(2048 * 1024 / 4 + 255) / 256, 256, 0, stream>>>(head_W, hWb, 2002, 10, 2048);
    k_convert_pad<<<(256 * 1024 / 4 + 255) / 256, 256, 0, stream>>>(proj0_W, p0Wb, 256, 10, 256);
    k_convert_pad<<<(8064 * 256 / 4 + 255) / 256, 256, 0, stream>>>(out0_W, o0Wb, 8000, 8, 8064);
    k_convert_pad<<<(128 * 1024 / 4 + 255) / 256, 256, 0, stream>>>(proj1_W, p1Wb, 64, 10, 128);
    k_convert_pad<<<(40320 * 64 / 4 + 255) / 256, 256, 0, stream>>>(out1_W, o1Wb, 40257, 6, 40320);
    k_tcols<<<8, 256, 0, stream>>>(targets, tc);

    // --- GEMMs ---
    // head: fused lse + target + routing cols 2000/2001
    k_gemm<1024, true><<<dim3(16, 16), 256, 0, stream>>>(
        xb, hWb, head_b, HEADSZ, ph, tc, tgh, 2000, r0, 2001, r1, nullptr, 0);
    // proj0 -> h0 bf16 [2048][256]
    k_gemm<1024, false><<<dim3(16, 2), 256, 0, stream>>>(
        xb, p0Wb, nullptr, 256, nullptr, nullptr, nullptr, -1, nullptr, -1, nullptr, h0b, 256);
    // out0: fused
    k_gemm<256, true><<<dim3(16, 63), 256, 0, stream>>>(
        h0b, o0Wb, nullptr, OSZ0, p0, tc + NROWS, tg0, -1, nullptr, -1, nullptr, nullptr, 0);
    // proj1 -> h1 bf16 [2048][64]
    k_gemm<1024, false><<<dim3(16, 1), 256, 0, stream>>>(
        xb, p1Wb, nullptr, 64, nullptr, nullptr, nullptr, -1, nullptr, -1, nullptr, h1b, 64);
    // out1: fused
    k_gemm<64, true><<<dim3(16, 315), 256, 0, stream>>>(
        h1b, o1Wb, nullptr, OSZ1, p1, tc + 2 * NROWS, tg1, -1, nullptr, -1, nullptr, nullptr, 0);

    // --- finalize ---
    float* outv = (float*)d_out;
    float* loss = (float*)d_out + NROWS;
    k_finalize<<<8, 256, 0, stream>>>(ph, p0, p1, tgh, r0, r1, tg0, tg1, targets, outv, bsum);
    k_loss<<<1, 1, 0, stream>>>(bsum, loss);
}

// Round 2
// 176.690 us; speedup vs baseline: 1.8156x; 1.8156x over previous
//
#include <hip/hip_runtime.h>
#include <hip/hip_bf16.h>

#define NROWS 2048

typedef float f32x4 __attribute__((ext_vector_type(4)));
typedef __bf16 bf16x8 __attribute__((ext_vector_type(8)));
typedef short s16x8 __attribute__((ext_vector_type(8)));

__device__ __forceinline__ unsigned short f2bf(float f) {
    unsigned int u = __float_as_uint(f);
    unsigned int r = (u + 0x7FFFu + ((u >> 16) & 1u)) >> 16;
    return (unsigned short)r;
}
__device__ __forceinline__ float bf2f(unsigned short u) {
    return __uint_as_float((unsigned int)u << 16);
}
__device__ __forceinline__ f32x4 mfma16(s16x8 a, s16x8 b, f32x4 c) {
    return __builtin_amdgcn_mfma_f32_16x16x32_bf16(
        __builtin_bit_cast(bf16x8, a), __builtin_bit_cast(bf16x8, b), c, 0, 0, 0);
}

// ---------------- gather x ----------------
__global__ void k_gather_x(const float* __restrict__ lhs, const int* __restrict__ idx,
                           unsigned short* __restrict__ xb) {
    int tid = blockIdx.x * 256 + threadIdx.x;
    int n = tid >> 8;
    int c = (tid & 255) << 2;
    int b = n >> 8, k = n & 255;
    int srow = idx[(b << 8) + k];
    const float4 v = *reinterpret_cast<const float4*>(
        lhs + (((size_t)b << 9) + srow) * 1024 + c);
    ushort4 o = make_ushort4(f2bf(v.x), f2bf(v.y), f2bf(v.z), f2bf(v.w));
    *reinterpret_cast<ushort4*>(xb + (size_t)n * 1024 + c) = o;
}

// ---------------- fused weight conversion ----------------
__global__ void k_convert_all(const float* __restrict__ hw, const float* __restrict__ p0w,
                              const float* __restrict__ p1w, const float* __restrict__ o0w,
                              const float* __restrict__ o1w,
                              unsigned short* __restrict__ hWb, unsigned short* __restrict__ pW01,
                              unsigned short* __restrict__ o0Wb, unsigned short* __restrict__ o1Wb) {
    const long B0 = 2048L * 1024;
    const long B1 = B0 + 320L * 1024;
    const long B2 = B1 + 8064L * 256;
    const long B3 = B2 + 40320L * 64;
    long e = ((long)blockIdx.x * 256 + threadIdx.x) * 4;
    if (e >= B3) return;
    const float* src; unsigned short* dst; long rows; int colshift; long base;
    if (e < B0)      { base = 0;  src = hw;  dst = hWb;  rows = 2002;  colshift = 10; }
    else if (e < B1) {
        long l = e - B0;
        if (l < 256L * 1024) { base = B0; src = p0w; dst = pW01; rows = 256; colshift = 10; }
        else { base = B0 + 256L * 1024; src = p1w; dst = pW01 + 256L * 1024; rows = 64; colshift = 10; }
    }
    else if (e < B2) { base = B1; src = o0w; dst = o0Wb; rows = 8000;  colshift = 8; }
    else             { base = B2; src = o1w; dst = o1Wb; rows = 40257; colshift = 6; }
    long l = e - base;
    long row = l >> colshift;
    ushort4 o;
    if (row < rows) {
        float4 v = *reinterpret_cast<const float4*>(src + l);
        o = make_ushort4(f2bf(v.x), f2bf(v.y), f2bf(v.z), f2bf(v.w));
    } else {
        o = make_ushort4(0, 0, 0, 0);
    }
    *reinterpret_cast<ushort4*>(dst + l) = o;
}

// ---------------- prep: padded bias + clipped target cols ----------------
__global__ void k_prep(const float* __restrict__ hb, const int* __restrict__ tgt,
                       float* __restrict__ bias_pad, int* __restrict__ tc) {
    int n = blockIdx.x * 256 + threadIdx.x;
    if (n >= 2048) return;
    bias_pad[n] = (n < 2002) ? hb[n] : -1e30f;
    int t = tgt[n];
    tc[n] = min(t, 1999);
    tc[2048 + n] = min(max(t - 2000, 0), 7999);
    tc[4096 + n] = min(max(t - 10000, 0), 40256);
}

// ---------------- head GEMM (2048x2048, K=1024) fused exp-sum ----------------
__global__ __launch_bounds__(256)
void k_head(const unsigned short* __restrict__ A, const unsigned short* __restrict__ B,
            const float* __restrict__ bias_pad, float* __restrict__ ph) {
    const int lane = threadIdx.x & 63, wid = threadIdx.x >> 6;
    const int wr = wid >> 1, wc = wid & 1;
    const int g = lane >> 4, cl = lane & 15;
    const int row0 = blockIdx.x * 64 + wr * 32;
    const int col0 = blockIdx.y * 64 + wc * 32;
    const unsigned short* Ap0 = A + (size_t)(row0 + cl) * 1024 + g * 8;
    const unsigned short* Ap1 = Ap0 + 16 * 1024;
    const unsigned short* Bp0 = B + (size_t)(col0 + cl) * 1024 + g * 8;
    const unsigned short* Bp1 = Bp0 + 16 * 1024;
    f32x4 acc[2][2] = {};
#pragma unroll 4
    for (int k = 0; k < 1024; k += 32) {
        s16x8 a0 = *reinterpret_cast<const s16x8*>(Ap0 + k);
        s16x8 a1 = *reinterpret_cast<const s16x8*>(Ap1 + k);
        s16x8 b0 = *reinterpret_cast<const s16x8*>(Bp0 + k);
        s16x8 b1 = *reinterpret_cast<const s16x8*>(Bp1 + k);
        acc[0][0] = mfma16(a0, b0, acc[0][0]);
        acc[0][1] = mfma16(a0, b1, acc[0][1]);
        acc[1][0] = mfma16(a1, b0, acc[1][0]);
        acc[1][1] = mfma16(a1, b1, acc[1][1]);
    }
    float bv0 = bias_pad[col0 + cl];
    float bv1 = bias_pad[col0 + 16 + cl];
#pragma unroll
    for (int mi = 0; mi < 2; ++mi) {
#pragma unroll
        for (int r = 0; r < 4; ++r) {
            float s = __expf(acc[mi][0][r] + bv0) + __expf(acc[mi][1][r] + bv1);
            s += __shfl_xor(s, 1, 64);
            s += __shfl_xor(s, 2, 64);
            s += __shfl_xor(s, 4, 64);
            s += __shfl_xor(s, 8, 64);
            if (cl == 0)
                ph[(size_t)(blockIdx.y * 2 + wc) * NROWS + row0 + mi * 16 + g * 4 + r] = s;
        }
    }
}

// ---------------- proj GEMM (2048x320, K=1024) -> bf16 h01 ----------------
__global__ __launch_bounds__(256)
void k_proj(const unsigned short* __restrict__ A, const unsigned short* __restrict__ B,
            unsigned short* __restrict__ h01) {
    const int lane = threadIdx.x & 63, wid = threadIdx.x >> 6;
    const int wr = wid >> 1, wc = wid & 1;
    const int g = lane >> 4, cl = lane & 15;
    const int row0 = blockIdx.x * 64 + wr * 32;
    const int col0 = blockIdx.y * 64 + wc * 32;
    const unsigned short* Ap0 = A + (size_t)(row0 + cl) * 1024 + g * 8;
    const unsigned short* Ap1 = Ap0 + 16 * 1024;
    const unsigned short* Bp0 = B + (size_t)(col0 + cl) * 1024 + g * 8;
    const unsigned short* Bp1 = Bp0 + 16 * 1024;
    f32x4 acc[2][2] = {};
#pragma unroll 4
    for (int k = 0; k < 1024; k += 32) {
        s16x8 a0 = *reinterpret_cast<const s16x8*>(Ap0 + k);
        s16x8 a1 = *reinterpret_cast<const s16x8*>(Ap1 + k);
        s16x8 b0 = *reinterpret_cast<const s16x8*>(Bp0 + k);
        s16x8 b1 = *reinterpret_cast<const s16x8*>(Bp1 + k);
        acc[0][0] = mfma16(a0, b0, acc[0][0]);
        acc[0][1] = mfma16(a0, b1, acc[0][1]);
        acc[1][0] = mfma16(a1, b0, acc[1][0]);
        acc[1][1] = mfma16(a1, b1, acc[1][1]);
    }
#pragma unroll
    for (int mi = 0; mi < 2; ++mi)
#pragma unroll
        for (int ni = 0; ni < 2; ++ni) {
            int col = col0 + ni * 16 + cl;
#pragma unroll
            for (int r = 0; r < 4; ++r) {
                int row = row0 + mi * 16 + g * 4 + r;
                h01[(size_t)row * 320 + col] = f2bf(acc[mi][ni][r]);
            }
        }
}

// ---------------- out0 panel GEMM (K=256, A in LDS) fused exp-sum ----------------
__global__ __launch_bounds__(256)
void k_out0(const unsigned short* __restrict__ h01, const unsigned short* __restrict__ B,
            float* __restrict__ p0) {
    extern __shared__ unsigned short As[];   // 128 x 264
    const int lane = threadIdx.x & 63, wid = threadIdx.x >> 6;
    const int wr = wid >> 1, wc = wid & 1;
    const int g = lane >> 4, cl = lane & 15;
    const int row0 = blockIdx.x * 128;
    {
        int r = threadIdx.x >> 1, half = threadIdx.x & 1;
        const unsigned short* src = h01 + (size_t)(row0 + r) * 320 + half * 128;
        unsigned short* dst = As + r * 264 + half * 128;
#pragma unroll
        for (int i = 0; i < 16; ++i)
            *reinterpret_cast<s16x8*>(dst + i * 8) =
                *reinterpret_cast<const s16x8*>(src + i * 8);
    }
    __syncthreads();
    float sexp[4][4] = {};
    const f32x4 z4 = {0.f, 0.f, 0.f, 0.f};
    const unsigned short* Al = As + (wr * 64 + cl) * 264 + g * 8;
    for (int it = 0; it < 2; ++it) {
        int tile = blockIdx.y * 2 + it;
        if (tile >= 63) break;
        int colb = tile * 128 + wc * 64;
        const unsigned short* Bp[4];
#pragma unroll
        for (int ni = 0; ni < 4; ++ni)
            Bp[ni] = B + (size_t)(colb + ni * 16 + cl) * 256 + g * 8;
        f32x4 acc[4][4];
#pragma unroll
        for (int kk = 0; kk < 8; ++kk) {
            s16x8 a[4], b[4];
#pragma unroll
            for (int mi = 0; mi < 4; ++mi)
                a[mi] = *reinterpret_cast<const s16x8*>(Al + mi * 16 * 264 + kk * 32);
#pragma unroll
            for (int ni = 0; ni < 4; ++ni)
                b[ni] = *reinterpret_cast<const s16x8*>(Bp[ni] + kk * 32);
            if (kk == 0) {
#pragma unroll
                for (int mi = 0; mi < 4; ++mi)
#pragma unroll
                    for (int ni = 0; ni < 4; ++ni)
                        acc[mi][ni] = mfma16(a[mi], b[ni], z4);
            } else {
#pragma unroll
                for (int mi = 0; mi < 4; ++mi)
#pragma unroll
                    for (int ni = 0; ni < 4; ++ni)
                        acc[mi][ni] = mfma16(a[mi], b[ni], acc[mi][ni]);
            }
        }
#pragma unroll
        for (int mi = 0; mi < 4; ++mi)
#pragma unroll
            for (int ni = 0; ni < 4; ++ni)
#pragma unroll
                for (int r = 0; r < 4; ++r)
                    sexp[mi][r] += __expf(acc[mi][ni][r]);
    }
#pragma unroll
    for (int mi = 0; mi < 4; ++mi)
#pragma unroll
        for (int r = 0; r < 4; ++r) {
            float s = sexp[mi][r];
            s += __shfl_xor(s, 1, 64);
            s += __shfl_xor(s, 2, 64);
            s += __shfl_xor(s, 4, 64);
            s += __shfl_xor(s, 8, 64);
            if (cl == 0)
                p0[(size_t)(blockIdx.y * 2 + wc) * NROWS + row0 + wr * 64 + mi * 16 + g * 4 + r] = s;
        }
}

// ---------------- out1 panel GEMM (K=64, A in regs) fused exp-sum ----------------
__global__ __launch_bounds__(256)
void k_out1(const unsigned short* __restrict__ h01, const unsigned short* __restrict__ B,
            float* __restrict__ p1) {
    const int lane = threadIdx.x & 63, wid = threadIdx.x >> 6;
    const int wr = wid >> 1, wc = wid & 1;
    const int g = lane >> 4, cl = lane & 15;
    const int row0 = blockIdx.x * 128 + wr * 64;
    s16x8 a[4][2];
#pragma unroll
    for (int mi = 0; mi < 4; ++mi)
#pragma unroll
        for (int kk = 0; kk < 2; ++kk)
            a[mi][kk] = *reinterpret_cast<const s16x8*>(
                h01 + (size_t)(row0 + mi * 16 + cl) * 320 + 256 + kk * 32 + g * 8);
    float sexp[4][4] = {};
    const f32x4 z4 = {0.f, 0.f, 0.f, 0.f};
    for (int it = 0; it < 9; ++it) {
        int colb = (blockIdx.y * 9 + it) * 128 + wc * 64;
        s16x8 b[4][2];
#pragma unroll
        for (int ni = 0; ni < 4; ++ni)
#pragma unroll
            for (int kk = 0; kk < 2; ++kk)
                b[ni][kk] = *reinterpret_cast<const s16x8*>(
                    B + (size_t)(colb + ni * 16 + cl) * 64 + kk * 32 + g * 8);
        f32x4 acc[4][4];
#pragma unroll
        for (int mi = 0; mi < 4; ++mi)
#pragma unroll
            for (int ni = 0; ni < 4; ++ni)
                acc[mi][ni] = mfma16(a[mi][0], b[ni][0], z4);
#pragma unroll
        for (int mi = 0; mi < 4; ++mi)
#pragma unroll
            for (int ni = 0; ni < 4; ++ni)
                acc[mi][ni] = mfma16(a[mi][1], b[ni][1], acc[mi][ni]);
#pragma unroll
        for (int mi = 0; mi < 4; ++mi)
#pragma unroll
            for (int ni = 0; ni < 4; ++ni)
#pragma unroll
                for (int r = 0; r < 4; ++r)
                    sexp[mi][r] += __expf(acc[mi][ni][r]);
    }
#pragma unroll
    for (int mi = 0; mi < 4; ++mi)
#pragma unroll
        for (int r = 0; r < 4; ++r) {
            float s = sexp[mi][r];
            s += __shfl_xor(s, 1, 64);
            s += __shfl_xor(s, 2, 64);
            s += __shfl_xor(s, 4, 64);
            s += __shfl_xor(s, 8, 64);
            if (cl == 0)
                p1[(size_t)(blockIdx.y * 2 + wc) * NROWS + row0 + mi * 16 + g * 4 + r] = s;
        }
}

// ---------------- per-row target / routing dots ----------------
__global__ __launch_bounds__(256)
void k_dots(const unsigned short* __restrict__ xb, const unsigned short* __restrict__ h01,
            const float* __restrict__ headW, const float* __restrict__ bias_pad,
            const float* __restrict__ o0w, const float* __restrict__ o1w,
            const int* __restrict__ tc,
            float* __restrict__ tgh, float* __restrict__ r0, float* __restrict__ r1,
            float* __restrict__ tg0, float* __restrict__ tg1) {
    int lane = threadIdx.x & 63;
    int n = (blockIdx.x * 256 + threadIdx.x) >> 6;
    int tch = tc[n], tc0 = tc[2048 + n], tc1 = tc[4096 + n];
    const unsigned short* xr = xb + (size_t)n * 1024 + lane * 16;
    s16x8 x0 = *reinterpret_cast<const s16x8*>(xr);
    s16x8 x1 = *reinterpret_cast<const s16x8*>(xr + 8);
    const float* wh = headW + (size_t)tch * 1024 + lane * 16;
    const float* wa = headW + (size_t)2000 * 1024 + lane * 16;
    const float* wb = headW + (size_t)2001 * 1024 + lane * 16;
    float dh = 0.f, da = 0.f, db = 0.f;
#pragma unroll
    for (int i = 0; i < 8; ++i) {
        float xv = bf2f((unsigned short)x0[i]);
        dh += xv * wh[i]; da += xv * wa[i]; db += xv * wb[i];
    }
#pragma unroll
    for (int i = 0; i < 8; ++i) {
        float xv = bf2f((unsigned short)x1[i]);
        dh += xv * wh[8 + i]; da += xv * wa[8 + i]; db += xv * wb[8 + i];
    }
    ushort4 h0v = *reinterpret_cast<const ushort4*>(h01 + (size_t)n * 320 + lane * 4);
    float4 w0v = *reinterpret_cast<const float4*>(o0w + (size_t)tc0 * 256 + lane * 4);
    float d2 = bf2f(h0v.x) * w0v.x + bf2f(h0v.y) * w0v.y +
               bf2f(h0v.z) * w0v.z + bf2f(h0v.w) * w0v.w;
    float d3 = bf2f(h01[(size_t)n * 320 + 256 + lane]) * o1w[(size_t)tc1 * 64 + lane];
#pragma unroll
    for (int m = 1; m < 64; m <<= 1) {
        dh += __shfl_xor(dh, m, 64);
        da += __shfl_xor(da, m, 64);
        db += __shfl_xor(db, m, 64);
        d2 += __shfl_xor(d2, m, 64);
        d3 += __shfl_xor(d3, m, 64);
    }
    if (lane == 0) {
        tgh[n] = dh + bias_pad[tch];
        r0[n] = da + bias_pad[2000];
        r1[n] = db + bias_pad[2001];
        tg0[n] = d2;
        tg1[n] = d3;
    }
}

// ---------------- finalize ----------------
__global__ void k_finalize(const float* __restrict__ ph, const float* __restrict__ p0,
                           const float* __restrict__ p1, const float* __restrict__ tgh,
                           const float* __restrict__ r0, const float* __restrict__ r1,
                           const float* __restrict__ tg0, const float* __restrict__ tg1,
                           const int* __restrict__ tgt, float* __restrict__ outv,
                           float* __restrict__ bsum) {
    int n = blockIdx.x * 128 + threadIdx.x;   // 16 blocks x 128
    float sh = 0.f, s0 = 0.f, s1 = 0.f;
    for (int s = 0; s < 64; ++s) sh += ph[(size_t)s * NROWS + n];
    for (int s = 0; s < 64; ++s) s0 += p0[(size_t)s * NROWS + n];
    for (int s = 0; s < 70; ++s) s1 += p1[(size_t)s * NROWS + n];
    s0 -= 64.f;   // zero-weight pad cols contribute exp(0)=1 each
    s1 -= 63.f;
    float lh = __logf(sh), l0 = __logf(s0), l1 = __logf(s1);
    int t = tgt[n];
    float o;
    if (t < 2000) o = tgh[n] - lh;
    else if (t < 10000) o = (r0[n] - lh) + (tg0[n] - l0);
    else o = (r1[n] - lh) + (tg1[n] - l1);
    outv[n] = o;
    __shared__ float red[128];
    red[threadIdx.x] = o;
    __syncthreads();
    for (int s = 64; s > 0; s >>= 1) {
        if (threadIdx.x < s) red[threadIdx.x] += red[threadIdx.x + s];
        __syncthreads();
    }
    if (threadIdx.x == 0) bsum[blockIdx.x] = red[0];
}

__global__ void k_loss(const float* __restrict__ bsum, float* __restrict__ loss) {
    float s = 0.f;
    for (int i = 0; i < 16; ++i) s += bsum[i];
    *loss = -s / (float)NROWS;
}

extern "C" void kernel_launch(void* const* d_in, const int* in_sizes, int n_in,
                              void* d_out, int out_size, void* d_ws, size_t ws_size,
                              hipStream_t stream) {
    const int* targets   = (const int*)d_in[0];
    const float* lhs     = (const float*)d_in[1];
    const int* idx       = (const int*)d_in[3];
    const float* head_W  = (const float*)d_in[4];
    const float* head_b  = (const float*)d_in[5];
    const float* proj0_W = (const float*)d_in[6];
    const float* out0_W  = (const float*)d_in[7];
    const float* proj1_W = (const float*)d_in[8];
    const float* out1_W  = (const float*)d_in[9];

    char* ws = (char*)d_ws;
    size_t off = 0;
    auto alloc = [&](size_t bytes) -> void* {
        void* p = ws + off;
        off += (bytes + 255) & ~(size_t)255;
        return p;
    };

    unsigned short* xb   = (unsigned short*)alloc((size_t)2048 * 1024 * 2);
    unsigned short* hWb  = (unsigned short*)alloc((size_t)2048 * 1024 * 2);
    unsigned short* pW01 = (unsigned short*)alloc((size_t)320 * 1024 * 2);
    unsigned short* o0Wb = (unsigned short*)alloc((size_t)8064 * 256 * 2);
    unsigned short* o1Wb = (unsigned short*)alloc((size_t)40320 * 64 * 2);
    unsigned short* h01  = (unsigned short*)alloc((size_t)2048 * 320 * 2);
    float* ph  = (float*)alloc((size_t)64 * 2048 * 4);
    float* p0  = (float*)alloc((size_t)64 * 2048 * 4);
    float* p1  = (float*)alloc((size_t)70 * 2048 * 4);
    float* tgh = (float*)alloc(2048 * 4);
    float* r0  = (float*)alloc(2048 * 4);
    float* r1  = (float*)alloc(2048 * 4);
    float* tg0 = (float*)alloc(2048 * 4);
    float* tg1 = (float*)alloc(2048 * 4);
    int*   tc  = (int*)alloc(3 * 2048 * 4);
    float* bias_pad = (float*)alloc(2048 * 4);
    float* bsum = (float*)alloc(16 * 4);

    k_convert_all<<<6904, 256, 0, stream>>>(head_W, proj0_W, proj1_W, out0_W, out1_W,
                                            hWb, pW01, o0Wb, o1Wb);
    k_gather_x<<<2048, 256, 0, stream>>>(lhs, idx, xb);
    k_prep<<<8, 256, 0, stream>>>(head_b, targets, bias_pad, tc);

    k_proj<<<dim3(32, 5), 256, 0, stream>>>(xb, pW01, h01);
    k_head<<<dim3(32, 32), 256, 0, stream>>>(xb, hWb, bias_pad, ph);
    k_dots<<<512, 256, 0, stream>>>(xb, h01, head_W, bias_pad, out0_W, out1_W, tc,
                                    tgh, r0, r1, tg0, tg1);
    k_out0<<<dim3(16, 32), 256, 128 * 264 * 2, stream>>>(h01, o0Wb, p0);
    k_out1<<<dim3(16, 35), 256, 0, stream>>>(h01, o1Wb, p1);

    float* outv = (float*)d_out;
    float* loss = (float*)d_out + NROWS;
    k_finalize<<<16, 128, 0, stream>>>(ph, p0, p1, tgh, r0, r1, tg0, tg1, targets, outv, bsum);
    k_loss<<<1, 1, 0, stream>>>(bsum, loss);
}

// Round 3
// 153.063 us; speedup vs baseline: 2.0959x; 1.1544x over previous
//
#include <hip/hip_runtime.h>
#include <hip/hip_bf16.h>

#define NROWS 2048

typedef float f32x4 __attribute__((ext_vector_type(4)));
typedef __bf16 bf16x8 __attribute__((ext_vector_type(8)));
typedef short s16x8 __attribute__((ext_vector_type(8)));

typedef const __attribute__((address_space(1))) unsigned int* gas_t;
typedef __attribute__((address_space(3))) unsigned int* las_t;

__device__ __forceinline__ unsigned short f2bf(float f) {
    unsigned int u = __float_as_uint(f);
    unsigned int r = (u + 0x7FFFu + ((u >> 16) & 1u)) >> 16;
    return (unsigned short)r;
}
__device__ __forceinline__ float bf2f(unsigned short u) {
    return __uint_as_float((unsigned int)u << 16);
}
__device__ __forceinline__ f32x4 mfma16(s16x8 a, s16x8 b, f32x4 c) {
    return __builtin_amdgcn_mfma_f32_16x16x32_bf16(
        __builtin_bit_cast(bf16x8, a), __builtin_bit_cast(bf16x8, b), c, 0, 0, 0);
}

// ---------------- gather x ----------------
__global__ void k_gather_x(const float* __restrict__ lhs, const int* __restrict__ idx,
                           unsigned short* __restrict__ xb) {
    int tid = blockIdx.x * 256 + threadIdx.x;
    int n = tid >> 8;
    int c = (tid & 255) << 2;
    int b = n >> 8, k = n & 255;
    int srow = idx[(b << 8) + k];
    const float4 v = *reinterpret_cast<const float4*>(
        lhs + (((size_t)b << 9) + srow) * 1024 + c);
    ushort4 o = make_ushort4(f2bf(v.x), f2bf(v.y), f2bf(v.z), f2bf(v.w));
    *reinterpret_cast<ushort4*>(xb + (size_t)n * 1024 + c) = o;
}

// ---------------- fused weight conversion ----------------
__global__ void k_convert_all(const float* __restrict__ hw, const float* __restrict__ p0w,
                              const float* __restrict__ p1w, const float* __restrict__ o0w,
                              const float* __restrict__ o1w,
                              unsigned short* __restrict__ hWb, unsigned short* __restrict__ pW01,
                              unsigned short* __restrict__ o0Wb, unsigned short* __restrict__ o1Wb) {
    const long B0 = 2048L * 1024;
    const long B1 = B0 + 384L * 1024;
    const long B2 = B1 + 8064L * 256;
    const long B3 = B2 + 40320L * 64;
    long e = ((long)blockIdx.x * 256 + threadIdx.x) * 4;
    if (e >= B3) return;
    const float* src; unsigned short* dst; long rows; int colshift; long base;
    if (e < B0)      { base = 0;  src = hw;  dst = hWb;  rows = 2002;  colshift = 10; }
    else if (e < B1) {
        long l = e - B0;
        long row = l >> 10;
        unsigned short* d = pW01 + l;
        ushort4 o;
        if (row < 256) {
            float4 v = *reinterpret_cast<const float4*>(p0w + l);
            o = make_ushort4(f2bf(v.x), f2bf(v.y), f2bf(v.z), f2bf(v.w));
        } else if (row < 320) {
            float4 v = *reinterpret_cast<const float4*>(p1w + (l - 256L * 1024));
            o = make_ushort4(f2bf(v.x), f2bf(v.y), f2bf(v.z), f2bf(v.w));
        } else {
            o = make_ushort4(0, 0, 0, 0);
        }
        *reinterpret_cast<ushort4*>(d) = o;
        return;
    }
    else if (e < B2) { base = B1; src = o0w; dst = o0Wb; rows = 8000;  colshift = 8; }
    else             { base = B2; src = o1w; dst = o1Wb; rows = 40257; colshift = 6; }
    long l = e - base;
    long row = l >> colshift;
    ushort4 o;
    if (row < rows) {
        float4 v = *reinterpret_cast<const float4*>(src + l);
        o = make_ushort4(f2bf(v.x), f2bf(v.y), f2bf(v.z), f2bf(v.w));
    } else {
        o = make_ushort4(0, 0, 0, 0);
    }
    *reinterpret_cast<ushort4*>(dst + l) = o;
}

// ---------------- prep: padded bias + clipped target cols ----------------
__global__ void k_prep(const float* __restrict__ hb, const int* __restrict__ tgt,
                       float* __restrict__ bias_pad, int* __restrict__ tc) {
    int n = blockIdx.x * 256 + threadIdx.x;
    if (n >= 2048) return;
    bias_pad[n] = (n < 2002) ? hb[n] : -1e30f;
    int t = tgt[n];
    tc[n] = min(t, 1999);
    tc[2048 + n] = min(max(t - 2000, 0), 7999);
    tc[4096 + n] = min(max(t - 10000, 0), 40256);
}

// ---------------- m97-style GEMM: 128x128 tile, BK=64, dbuf global_load_lds ----------
// A [2048][lda] bf16 (rows), B [cols_pad][ldb] bf16 (output cols as rows).
// MODE 0: store bf16 hout[row][col] (col < hcols). MODE 1: fused exp-sum per
// 64-col strip -> partial[strip][row], optional bias (head).
template <int NT, int MODE>
__global__ __launch_bounds__(256)
void k_mm(const unsigned short* __restrict__ A, int lda,
          const unsigned short* __restrict__ B, int ldb,
          const float* __restrict__ bias, float* __restrict__ partial,
          unsigned short* __restrict__ hout, int hstride, int hcols) {
    __shared__ unsigned short As[2][128 * 64];
    __shared__ unsigned short Bs[2][128 * 64];
    const int tid = threadIdx.x;
    const int lane = tid & 63, wid = tid >> 6;
    const int wr = wid >> 1, wc = wid & 1;
    const int g = lane >> 4, cl = lane & 15;
    const int row0 = blockIdx.x * 128;
    const int col0 = blockIdx.y * 128;

    const int sr = wid * 8 + (lane >> 3);     // staging row 0..31 per issue group
    const int skc = (lane & 7) * 8;           // staging k-col (elems)
    const unsigned short* Ab = A + (size_t)row0 * lda + skc;
    const unsigned short* Bb = B + (size_t)col0 * ldb + skc;

    auto stage = [&](int buf, int kt) {
        const unsigned short* ga = Ab + (size_t)sr * lda + kt;
        const unsigned short* gb = Bb + (size_t)sr * ldb + kt;
        unsigned short* la = &As[buf][wid * 8 * 64];
        unsigned short* lb = &Bs[buf][wid * 8 * 64];
#pragma unroll
        for (int i = 0; i < 4; ++i) {
            __builtin_amdgcn_global_load_lds((gas_t)(const void*)(ga + (size_t)i * 32 * lda),
                                             (las_t)(void*)(la + i * 32 * 64), 16, 0, 0);
            __builtin_amdgcn_global_load_lds((gas_t)(const void*)(gb + (size_t)i * 32 * ldb),
                                             (las_t)(void*)(lb + i * 32 * 64), 16, 0, 0);
        }
    };

    f32x4 acc[4][4] = {};
    stage(0, 0);
    asm volatile("s_waitcnt vmcnt(0)" ::: "memory");
    __syncthreads();
    for (int t = 0; t < NT; ++t) {
        if (t + 1 < NT) stage((t + 1) & 1, (t + 1) * 64);
        const unsigned short* Al = &As[t & 1][(wr * 64 + cl) * 64 + g * 8];
        const unsigned short* Bl = &Bs[t & 1][(wc * 64 + cl) * 64 + g * 8];
#pragma unroll
        for (int kk = 0; kk < 64; kk += 32) {
            s16x8 a[4], b[4];
#pragma unroll
            for (int mi = 0; mi < 4; ++mi)
                a[mi] = *reinterpret_cast<const s16x8*>(Al + mi * 16 * 64 + kk);
#pragma unroll
            for (int ni = 0; ni < 4; ++ni)
                b[ni] = *reinterpret_cast<const s16x8*>(Bl + ni * 16 * 64 + kk);
#pragma unroll
            for (int mi = 0; mi < 4; ++mi)
#pragma unroll
                for (int ni = 0; ni < 4; ++ni)
                    acc[mi][ni] = mfma16(a[mi], b[ni], acc[mi][ni]);
        }
        if (t + 1 < NT) {
            asm volatile("s_waitcnt vmcnt(0)" ::: "memory");
            __syncthreads();
        }
    }

    if (MODE == 0) {
#pragma unroll
        for (int mi = 0; mi < 4; ++mi)
#pragma unroll
            for (int ni = 0; ni < 4; ++ni) {
                int col = col0 + wc * 64 + ni * 16 + cl;
                if (col < hcols) {
#pragma unroll
                    for (int r = 0; r < 4; ++r) {
                        int row = row0 + wr * 64 + mi * 16 + g * 4 + r;
                        hout[(size_t)row * hstride + col] = f2bf(acc[mi][ni][r]);
                    }
                }
            }
    } else {
        float bv[4];
#pragma unroll
        for (int ni = 0; ni < 4; ++ni)
            bv[ni] = bias ? bias[col0 + wc * 64 + ni * 16 + cl] : 0.f;
        int strip = blockIdx.y * 2 + wc;
#pragma unroll
        for (int mi = 0; mi < 4; ++mi)
#pragma unroll
            for (int r = 0; r < 4; ++r) {
                float s = 0.f;
#pragma unroll
                for (int ni = 0; ni < 4; ++ni)
                    s += __expf(acc[mi][ni][r] + bv[ni]);
                s += __shfl_xor(s, 1, 64);
                s += __shfl_xor(s, 2, 64);
                s += __shfl_xor(s, 4, 64);
                s += __shfl_xor(s, 8, 64);
                if (cl == 0)
                    partial[(size_t)strip * NROWS + row0 + wr * 64 + mi * 16 + g * 4 + r] = s;
            }
    }
}

// ---------------- out1 panel GEMM (K=64, A in regs) fused exp-sum ----------------
__global__ __launch_bounds__(256)
void k_out1(const unsigned short* __restrict__ h01, const unsigned short* __restrict__ B,
            float* __restrict__ p1) {
    const int lane = threadIdx.x & 63, wid = threadIdx.x >> 6;
    const int wr = wid >> 1, wc = wid & 1;
    const int g = lane >> 4, cl = lane & 15;
    const int row0 = blockIdx.x * 128 + wr * 64;
    s16x8 a[4][2];
#pragma unroll
    for (int mi = 0; mi < 4; ++mi)
#pragma unroll
        for (int kk = 0; kk < 2; ++kk)
            a[mi][kk] = *reinterpret_cast<const s16x8*>(
                h01 + (size_t)(row0 + mi * 16 + cl) * 320 + 256 + kk * 32 + g * 8);
    float sexp[4][4] = {};
    const f32x4 z4 = {0.f, 0.f, 0.f, 0.f};
    for (int it = 0; it < 9; ++it) {
        int colb = (blockIdx.y * 9 + it) * 128 + wc * 64;
        s16x8 b[4][2];
#pragma unroll
        for (int ni = 0; ni < 4; ++ni)
#pragma unroll
            for (int kk = 0; kk < 2; ++kk)
                b[ni][kk] = *reinterpret_cast<const s16x8*>(
                    B + (size_t)(colb + ni * 16 + cl) * 64 + kk * 32 + g * 8);
        f32x4 acc[4][4];
#pragma unroll
        for (int mi = 0; mi < 4; ++mi)
#pragma unroll
            for (int ni = 0; ni < 4; ++ni)
                acc[mi][ni] = mfma16(a[mi][0], b[ni][0], z4);
#pragma unroll
        for (int mi = 0; mi < 4; ++mi)
#pragma unroll
            for (int ni = 0; ni < 4; ++ni)
                acc[mi][ni] = mfma16(a[mi][1], b[ni][1], acc[mi][ni]);
#pragma unroll
        for (int mi = 0; mi < 4; ++mi)
#pragma unroll
            for (int ni = 0; ni < 4; ++ni)
#pragma unroll
                for (int r = 0; r < 4; ++r)
                    sexp[mi][r] += __expf(acc[mi][ni][r]);
    }
#pragma unroll
    for (int mi = 0; mi < 4; ++mi)
#pragma unroll
        for (int r = 0; r < 4; ++r) {
            float s = sexp[mi][r];
            s += __shfl_xor(s, 1, 64);
            s += __shfl_xor(s, 2, 64);
            s += __shfl_xor(s, 4, 64);
            s += __shfl_xor(s, 8, 64);
            if (cl == 0)
                p1[(size_t)(blockIdx.y * 2 + wc) * NROWS + row0 + mi * 16 + g * 4 + r] = s;
        }
}

// ---------------- per-row target / routing dots ----------------
__global__ __launch_bounds__(256)
void k_dots(const unsigned short* __restrict__ xb, const unsigned short* __restrict__ h01,
            const float* __restrict__ headW, const float* __restrict__ bias_pad,
            const float* __restrict__ o0w, const float* __restrict__ o1w,
            const int* __restrict__ tc,
            float* __restrict__ tgh, float* __restrict__ r0, float* __restrict__ r1,
            float* __restrict__ tg0, float* __restrict__ tg1) {
    int lane = threadIdx.x & 63;
    int n = (blockIdx.x * 256 + threadIdx.x) >> 6;
    int tch = tc[n], tc0 = tc[2048 + n], tc1 = tc[4096 + n];
    const unsigned short* xr = xb + (size_t)n * 1024 + lane * 16;
    s16x8 x0 = *reinterpret_cast<const s16x8*>(xr);
    s16x8 x1 = *reinterpret_cast<const s16x8*>(xr + 8);
    const float* wh = headW + (size_t)tch * 1024 + lane * 16;
    const float* wa = headW + (size_t)2000 * 1024 + lane * 16;
    const float* wb = headW + (size_t)2001 * 1024 + lane * 16;
    float dh = 0.f, da = 0.f, db = 0.f;
#pragma unroll
    for (int i = 0; i < 8; ++i) {
        float xv = bf2f((unsigned short)x0[i]);
        dh += xv * wh[i]; da += xv * wa[i]; db += xv * wb[i];
    }
#pragma unroll
    for (int i = 0; i < 8; ++i) {
        float xv = bf2f((unsigned short)x1[i]);
        dh += xv * wh[8 + i]; da += xv * wa[8 + i]; db += xv * wb[8 + i];
    }
    ushort4 h0v = *reinterpret_cast<const ushort4*>(h01 + (size_t)n * 320 + lane * 4);
    float4 w0v = *reinterpret_cast<const float4*>(o0w + (size_t)tc0 * 256 + lane * 4);
    float d2 = bf2f(h0v.x) * w0v.x + bf2f(h0v.y) * w0v.y +
               bf2f(h0v.z) * w0v.z + bf2f(h0v.w) * w0v.w;
    float d3 = bf2f(h01[(size_t)n * 320 + 256 + lane]) * o1w[(size_t)tc1 * 64 + lane];
#pragma unroll
    for (int m = 1; m < 64; m <<= 1) {
        dh += __shfl_xor(dh, m, 64);
        da += __shfl_xor(da, m, 64);
        db += __shfl_xor(db, m, 64);
        d2 += __shfl_xor(d2, m, 64);
        d3 += __shfl_xor(d3, m, 64);
    }
    if (lane == 0) {
        tgh[n] = dh + bias_pad[tch];
        r0[n] = da + bias_pad[2000];
        r1[n] = db + bias_pad[2001];
        tg0[n] = d2;
        tg1[n] = d3;
    }
}

// ---------------- finalize ----------------
__global__ void k_finalize(const float* __restrict__ ph, const float* __restrict__ p0,
                           const float* __restrict__ p1, const float* __restrict__ tgh,
                           const float* __restrict__ r0, const float* __restrict__ r1,
                           const float* __restrict__ tg0, const float* __restrict__ tg1,
                           const int* __restrict__ tgt, float* __restrict__ outv,
                           float* __restrict__ bsum) {
    int n = blockIdx.x * 128 + threadIdx.x;   // 16 blocks x 128
    float sh = 0.f, s0 = 0.f, s1 = 0.f;
    for (int s = 0; s < 32; ++s) sh += ph[(size_t)s * NROWS + n];
    for (int s = 0; s < 126; ++s) s0 += p0[(size_t)s * NROWS + n];
    for (int s = 0; s < 70; ++s) s1 += p1[(size_t)s * NROWS + n];
    s0 -= 64.f;   // zero-weight pad cols contribute exp(0)=1 each
    s1 -= 63.f;
    float lh = __logf(sh), l0 = __logf(s0), l1 = __logf(s1);
    int t = tgt[n];
    float o;
    if (t < 2000) o = tgh[n] - lh;
    else if (t < 10000) o = (r0[n] - lh) + (tg0[n] - l0);
    else o = (r1[n] - lh) + (tg1[n] - l1);
    outv[n] = o;
    __shared__ float red[128];
    red[threadIdx.x] = o;
    __syncthreads();
    for (int s = 64; s > 0; s >>= 1) {
        if (threadIdx.x < s) red[threadIdx.x] += red[threadIdx.x + s];
        __syncthreads();
    }
    if (threadIdx.x == 0) bsum[blockIdx.x] = red[0];
}

__global__ void k_loss(const float* __restrict__ bsum, float* __restrict__ loss) {
    float s = 0.f;
    for (int i = 0; i < 16; ++i) s += bsum[i];
    *loss = -s / (float)NROWS;
}

extern "C" void kernel_launch(void* const* d_in, const int* in_sizes, int n_in,
                              void* d_out, int out_size, void* d_ws, size_t ws_size,
                              hipStream_t stream) {
    const int* targets   = (const int*)d_in[0];
    const float* lhs     = (const float*)d_in[1];
    const int* idx       = (const int*)d_in[3];
    const float* head_W  = (const float*)d_in[4];
    const float* head_b  = (const float*)d_in[5];
    const float* proj0_W = (const float*)d_in[6];
    const float* out0_W  = (const float*)d_in[7];
    const float* proj1_W = (const float*)d_in[8];
    const float* out1_W  = (const float*)d_in[9];

    char* ws = (char*)d_ws;
    size_t off = 0;
    auto alloc = [&](size_t bytes) -> void* {
        void* p = ws + off;
        off += (bytes + 255) & ~(size_t)255;
        return p;
    };

    unsigned short* xb   = (unsigned short*)alloc((size_t)2048 * 1024 * 2);
    unsigned short* hWb  = (unsigned short*)alloc((size_t)2048 * 1024 * 2);
    unsigned short* pW01 = (unsigned short*)alloc((size_t)384 * 1024 * 2);   // 256 p0 + 64 p1 + 64 pad
    unsigned short* o0Wb = (unsigned short*)alloc((size_t)8064 * 256 * 2);
    unsigned short* o1Wb = (unsigned short*)alloc((size_t)40320 * 64 * 2);
    unsigned short* h01  = (unsigned short*)alloc((size_t)2048 * 320 * 2);
    float* ph  = (float*)alloc((size_t)32 * 2048 * 4);
    float* p0  = (float*)alloc((size_t)126 * 2048 * 4);
    float* p1  = (float*)alloc((size_t)70 * 2048 * 4);
    float* tgh = (float*)alloc(2048 * 4);
    float* r0  = (float*)alloc(2048 * 4);
    float* r1  = (float*)alloc(2048 * 4);
    float* tg0 = (float*)alloc(2048 * 4);
    float* tg1 = (float*)alloc(2048 * 4);
    int*   tc  = (int*)alloc(3 * 2048 * 4);
    float* bias_pad = (float*)alloc(2048 * 4);
    float* bsum = (float*)alloc(16 * 4);

    k_gather_x<<<2048, 256, 0, stream>>>(lhs, idx, xb);
    k_convert_all<<<6968, 256, 0, stream>>>(head_W, proj0_W, proj1_W, out0_W, out1_W,
                                            hWb, pW01, o0Wb, o1Wb);
    k_prep<<<8, 256, 0, stream>>>(head_b, targets, bias_pad, tc);

    // proj: 2048 x 384(valid 320), K=1024 -> h01 bf16
    k_mm<16, 0><<<dim3(16, 3), 256, 0, stream>>>(
        xb, 1024, pW01, 1024, nullptr, nullptr, h01, 320, 320);
    // head: 2048 x 2048, K=1024, fused exp-sum (32 strips)
    k_mm<16, 1><<<dim3(16, 16), 256, 0, stream>>>(
        xb, 1024, hWb, 1024, bias_pad, ph, nullptr, 0, 0);
    // out0: 2048 x 8064, K=256, fused exp-sum (126 strips)
    k_mm<4, 1><<<dim3(16, 63), 256, 0, stream>>>(
        h01, 320, o0Wb, 256, nullptr, p0, nullptr, 0, 0);
    // out1: 2048 x 40320, K=64, fused exp-sum (70 strips)
    k_out1<<<dim3(16, 35), 256, 0, stream>>>(h01, o1Wb, p1);

    k_dots<<<512, 256, 0, stream>>>(xb, h01, head_W, bias_pad, out0_W, out1_W, tc,
                                    tgh, r0, r1, tg0, tg1);

    float* outv = (float*)d_out;
    float* loss = (float*)d_out + NROWS;
    k_finalize<<<16, 128, 0, stream>>>(ph, p0, p1, tgh, r0, r1, tg0, tg1, targets, outv, bsum);
    k_loss<<<1, 1, 0, stream>>>(bsum, loss);
}